// Round 6
// baseline (159.882 us; speedup 1.0000x reference)
//
#include <hip/hip_runtime.h>
#include <hip/hip_bf16.h>
#include <math.h>

typedef __bf16 bhalf;
typedef __bf16 bhalf8 __attribute__((ext_vector_type(8)));
typedef float floatx4 __attribute__((ext_vector_type(4)));
typedef _Float16 fh;
typedef _Float16 half2 __attribute__((ext_vector_type(2)));
typedef _Float16 half4 __attribute__((ext_vector_type(4)));

#define MFMA_BF16(A, B, C) __builtin_amdgcn_mfma_f32_16x16x32_bf16((A), (B), (C), 0, 0, 0)
#define MFMA_F16_K16(A, B, C) __builtin_amdgcn_mfma_f32_16x16x16f16((A), (B), (C), 0, 0, 0)

__device__ inline unsigned short bfb(float f) {
  union { bhalf h; unsigned short u; } c;
  c.h = (bhalf)f;
  return c.u;
}
__device__ inline unsigned short fhb(float f) {
  union { fh h; unsigned short u; } c;
  c.h = (fh)f;
  return c.u;
}
__device__ inline half2 cvt_pk_f16(float a, float b) {
  return __builtin_bit_cast(half2, __builtin_amdgcn_cvt_pkrtz(a, b));
}

// async global->LDS, 16B per lane; HW uses wave-uniform LDS base + lane*16
__device__ inline void gload_lds16(const void* g, void* l) {
  typedef const __attribute__((address_space(1))) unsigned int GU;
  typedef __attribute__((address_space(3))) unsigned int LU;
  __builtin_amdgcn_global_load_lds((GU*)g, (LU*)l, 16, 0, 0);
}

// ---------------- fused prep: cvt x (fp32->bf16) + both weight transposes -------
// blocks [0,2048): cvt_x ; [2048,5120): w_qkv^T ; [5120,6144): w_o^T
__global__ __launch_bounds__(256) void prep_kernel(const float* __restrict__ x,
                                                   const float* __restrict__ wqkv,
                                                   const float* __restrict__ wo,
                                                   bhalf* __restrict__ x_bf,
                                                   bhalf* __restrict__ wqkvT,
                                                   bhalf* __restrict__ woT) {
  __shared__ float tile[32][33];
  const int bx = blockIdx.x;
  if (bx < 2048) {
    int i = (bx * 256 + threadIdx.x) * 8;
    floatx4 v0 = *(const floatx4*)(x + i);
    floatx4 v1 = *(const floatx4*)(x + i + 4);
    bhalf8 o;
    o[0] = (bhalf)v0[0]; o[1] = (bhalf)v0[1]; o[2] = (bhalf)v0[2]; o[3] = (bhalf)v0[3];
    o[4] = (bhalf)v1[0]; o[5] = (bhalf)v1[1]; o[6] = (bhalf)v1[2]; o[7] = (bhalf)v1[3];
    *(bhalf8*)(x_bf + i) = o;
    return;
  }
  const float* in;
  bhalf* out;
  int C, cx, ry;
  if (bx < 5120) {
    int idx = bx - 2048;
    in = wqkv; out = wqkvT; C = 3072;
    cx = idx % 96; ry = idx / 96;
  } else {
    int idx = bx - 5120;
    in = wo; out = woT; C = 1024;
    cx = idx & 31; ry = idx >> 5;
  }
  const int R = 1024;
  int c0 = cx * 32, r0 = ry * 32;
  int tx = threadIdx.x & 31, ty = threadIdx.x >> 5;
#pragma unroll
  for (int i = 0; i < 32; i += 8)
    tile[ty + i][tx] = in[(size_t)(r0 + ty + i) * C + c0 + tx];
  __syncthreads();
#pragma unroll
  for (int i = 0; i < 32; i += 8)
    out[(size_t)(c0 + ty + i) * R + r0 + tx] = (bhalf)tile[tx][ty + i];
}

// ---------------- GEMM: C[M,N] = A[M,K] * BT[N,K]^T  (bf16 in, fp32 acc) --------
// r5 structure (proven fastest): BK=64, SINGLE 32KB LDS buffer, 2 barriers/iter,
// co-resident blocks do the latency hiding.
// EPI=0: plain fp32 store. EPI=1: RoPE + scatter q,k->[b,h,s,d] bf16; v->[b,h,d,s] f16.
//        q additionally pre-scaled by 0.125*log2(e) for the attention kernel.
// r10: RoPE via __sincosf base + 3-step angle-addition recurrence: 64->20
//      transcendental pairs per lane (f32 recurrence error << bf16 rounding).
template <int EPI, int TN>
__global__ __launch_bounds__(256, 2) void gemm_bt_kernel(
    const bhalf* __restrict__ A, const bhalf* __restrict__ BT, float* __restrict__ Cout,
    bhalf* __restrict__ qb, bhalf* __restrict__ kb, fh* __restrict__ vb,
    int M, int N, int K) {
  constexpr int NT = TN / 32;
  __shared__ __attribute__((aligned(16))) bhalf As[128 * 64];  // 16 KB
  __shared__ __attribute__((aligned(16))) bhalf Bs[TN * 64];   // 16/8 KB
  const int tid = threadIdx.x;
  const int lane = tid & 63;
  const int w = tid >> 6, wr = w >> 1, wc = w & 1;
  const int m0 = blockIdx.y * 128, n0 = blockIdx.x * TN;
  const int l15 = lane & 15, lhi = lane >> 4;

  floatx4 acc[4][NT];
#pragma unroll
  for (int i = 0; i < 4; ++i)
#pragma unroll
    for (int j = 0; j < NT; ++j) acc[i][j] = (floatx4){0.f, 0.f, 0.f, 0.f};

  const int srow16 = lane >> 2;
  const int scg = (lane & 3) ^ ((lane >> 3) & 3);
  const bhalf* aP0 = A + (size_t)(m0 + 32 * w + srow16) * K + scg * 8;
  const bhalf* aP1 = aP0 + (size_t)16 * K;
  const bhalf* bP0 = BT + (size_t)(n0 + ((TN == 128) ? 32 * w : 16 * w) + srow16) * K + scg * 8;
  const bhalf* bP1 = bP0 + (size_t)16 * K;
  bhalf* aL0 = &As[(2 * w) * 512];
  bhalf* aL1 = &As[(2 * w + 1) * 512];
  bhalf* bL0 = (TN == 128) ? &Bs[(2 * w) * 512] : &Bs[w * 512];
  bhalf* bL1 = (TN == 128) ? &Bs[(2 * w + 1) * 512] : nullptr;

  const int fro = (l15 * 4 + (lhi ^ ((l15 >> 1) & 3))) * 8;

  for (int k0 = 0; k0 < K; k0 += 64) {
    __syncthreads();
    // k-half 0 (cols k0..k0+31)
    gload_lds16(aP0 + k0, aL0);
    gload_lds16(aP1 + k0, aL1);
    gload_lds16(bP0 + k0, bL0);
    if constexpr (TN == 128) gload_lds16(bP1 + k0, bL1);
    // k-half 1 (cols k0+32..k0+63) -> LDS +4096 (A) / +TN*32 (B)
    gload_lds16(aP0 + k0 + 32, aL0 + 4096);
    gload_lds16(aP1 + k0 + 32, aL1 + 4096);
    gload_lds16(bP0 + k0 + 32, bL0 + TN * 32);
    if constexpr (TN == 128) gload_lds16(bP1 + k0 + 32, bL1 + TN * 32);
    __syncthreads();
#pragma unroll
    for (int kh = 0; kh < 2; ++kh) {
      bhalf8 af[4], bf[NT];
#pragma unroll
      for (int mt = 0; mt < 4; ++mt)
        af[mt] = *(const bhalf8*)&As[kh * 4096 + (wr * 4 + mt) * 512 + fro];
#pragma unroll
      for (int nt = 0; nt < NT; ++nt)
        bf[nt] = *(const bhalf8*)&Bs[kh * TN * 32 + (wc * NT + nt) * 512 + fro];
#pragma unroll
      for (int mt = 0; mt < 4; ++mt)
#pragma unroll
        for (int nt = 0; nt < NT; ++nt)
          acc[mt][nt] = MFMA_BF16(af[mt], bf[nt], acc[mt][nt]);
    }
  }

  if constexpr (EPI == 0) {
#pragma unroll
    for (int mt = 0; mt < 4; ++mt)
#pragma unroll
      for (int nt = 0; nt < NT; ++nt)
#pragma unroll
        for (int r = 0; r < 4; ++r) {
          int mg = m0 + wr * 64 + mt * 16 + lhi * 4 + r;
          int ng = n0 + wc * (TN / 2) + nt * 16 + l15;
          Cout[(size_t)mg * N + ng] = acc[mt][nt][r];
        }
  } else {
    const int sel = n0 >> 10;  // block-uniform: 0=q, 1=k, 2=v
    if (sel == 2) {
      // v: store transposed [b,h,d,s] as f16 -- 4 s-contiguous per lane = 8B store
#pragma unroll
      for (int mt = 0; mt < 4; ++mt) {
        int mg = m0 + wr * 64 + mt * 16 + lhi * 4;
        int b = mg >> 11, s0 = mg & 2047;
#pragma unroll
        for (int nt = 0; nt < NT; ++nt) {
          int ng = n0 + wc * (TN / 2) + nt * 16 + l15;
          int h = (ng & 1023) >> 6, d = ng & 63;
          union { unsigned short u[4]; uint2 v2; } pk;
#pragma unroll
          for (int r = 0; r < 4; ++r) pk.u[r] = fhb(acc[mt][nt][r]);
          *(uint2*)&vb[((size_t)((b << 4) + h) * 64 + d) * 2048 + s0] = pk.v2;
        }
      }
    } else {
      bhalf* dst = sel ? kb : qb;
      const float post = sel ? 1.0f : 0.18033688f;  // q pre-scaled by 0.125*log2(e)
#pragma unroll
      for (int nt = 0; nt < NT; ++nt) {
        int ng = n0 + wc * (TN / 2) + nt * 16 + l15;
        int h = (ng & 1023) >> 6, d = ng & 63;
        float inv = exp2f((float)(d >> 1) * -0.4152410118609203f);
        float si, ci;
        __sincosf(inv, &si, &ci);  // per-row rotation step
#pragma unroll
        for (int mt = 0; mt < 4; ++mt) {
          int mg = m0 + wr * 64 + mt * 16 + lhi * 4;
          int b = mg >> 11, s0 = mg & 2047;
          float sn, cs;
          __sincosf((float)s0 * inv, &sn, &cs);
#pragma unroll
          for (int r = 0; r < 4; ++r) {
            float val = acc[mt][nt][r];
            float partner = __shfl_xor(val, 1, 64);  // pair column d^1 lives in lane^1
            if (!(l15 & 1)) {
              float oe = (cs * val - sn * partner) * post;
              float oo = (cs * partner + sn * val) * post;
              unsigned int u = bfb(oe) | ((unsigned int)bfb(oo) << 16);
              *(unsigned int*)&dst[((size_t)((b << 4) + h) * 2048 + (s0 + r)) * 64 + d] = u;
            }
            // angle-addition recurrence: (cs,sn) <- rot by inv
            float cs2 = cs * ci - sn * si;
            sn = sn * ci + cs * si;
            cs = cs2;
          }
        }
      }
    }
  }
}

// ---------------- flash sliding-window attention ----------------
// grid (B*H, S/128), 256 thr = 4 waves. Q-tile 128 rows (two 64-halves share the
// staged K/V and the LDS fragment reads). S^T trick (A=K,B=Q): C-layout == f16
// B-operand layout -> P stays in registers. No-max softmax; q pre-scaled.
// r11 (T4 counted-vmcnt pipeline):
//   - 4 LDS buffers (64KB), prefetch depth 2, ONE raw s_barrier per tile.
//   - steady-state `s_waitcnt vmcnt(8)` (2 stages x 4 loads in flight) instead of
//     __syncthreads' vmcnt(0) drain -- prefetches survive the barrier (T4, m218).
//   - hazard analysis: stage(i+2) writes buf[(i+2)&3]; its previous readers were
//     proc(i-2), complete before barrier(i-1) which every wave passed before the
//     stage issue -> bottom barrier redundant with 4 buffers (NOT with 3).
//   - prologue __syncthreads() drains Q-fragment loads once, so the compiler's
//     waitcnt bookkeeping doesn't inject conservative drains in the loop.
//   - occupancy 2 blocks/CU (LDS-limited); overlap replaces the lost TLP (r7).
__global__ __launch_bounds__(256, 2) void attn_kernel(const bhalf* __restrict__ qg,
                                                      const bhalf* __restrict__ kg,
                                                      const fh* __restrict__ vt,
                                                      bhalf* __restrict__ attn_out) {
  __shared__ __attribute__((aligned(16))) bhalf Ks[4][8 * 512];  // 4 x 8 KB
  __shared__ __attribute__((aligned(16))) fh Vs[4][16 * 256];    // 4 x 8 KB

  const int bh = blockIdx.x;    // b*16+h
  const int qt2 = blockIdx.y;   // 128-row q tile
  const int tid = threadIdx.x, lane = tid & 63, w = tid >> 6;
  const int l15 = lane & 15, quad = lane >> 4;
  const int q0 = qt2 * 128;
  const int qtile0 = qt2 * 2;   // 64-granular tile index of first half (even)
  const size_t base = (size_t)bh * 2048 * 64;   // q,k: [bh][s][d]
  const size_t vbase = (size_t)bh * 64 * 2048;  // vt:  [bh][d][s]

  // Q B-fragments for both halves (already scaled by 0.125*log2e in qkv epilogue)
  bhalf8 qa[2][2];
#pragma unroll
  for (int h = 0; h < 2; ++h) {
    const bhalf* qp = qg + base + (size_t)(q0 + h * 64 + w * 16 + l15) * 64 + quad * 8;
    qa[h][0] = *(const bhalf8*)qp;
    qa[h][1] = *(const bhalf8*)(qp + 32);
  }

  // DMA lane-geometry (tile-offset-independent)
  const int kOff = (w * 16 + (lane >> 2)) * 64 + (lane & 3) * 8;
  const int vfb0 = 4 * w + (lane >> 5), vfb1 = 4 * w + 2 + (lane >> 5);
  const int vOff0 = ((vfb0 & 3) * 16 + ((lane & 31) >> 1)) * 2048 + w * 16 + (lane & 1) * 8;
  const int vOff1 = ((vfb1 & 3) * 16 + ((lane & 31) >> 1)) * 2048 + w * 16 + (lane & 1) * 8;

  floatx4 O[2][4];
#pragma unroll
  for (int h = 0; h < 2; ++h)
#pragma unroll
    for (int dt = 0; dt < 4; ++dt) O[h][dt] = (floatx4){0.f, 0.f, 0.f, 0.f};
  float lsum[2] = {0.f, 0.f};

  auto stage = [&](int kt, int buf) {  // 4 gload_lds16 per wave
    const bhalf* kp = kg + base + (size_t)(kt * 64) * 64 + kOff;
    gload_lds16(kp, &Ks[buf][(2 * w) * 512]);
    gload_lds16(kp + 32, &Ks[buf][(2 * w + 1) * 512]);
    const fh* vp = vt + vbase + kt * 64;
    gload_lds16(vp + vOff0, &Vs[buf][(2 * w) * 512]);
    gload_lds16(vp + vOff1, &Vs[buf][(2 * w + 1) * 512]);
  };

  // one 64-key tile, BOTH q-halves, sharing every K/V fragment read
  auto proc2 = [&](int buf, int kt) {
    const bool va = (kt <= qtile0) && (kt >= qtile0 - 8);      // h=0 valid
    const bool vb_ = (kt <= qtile0 + 1) && (kt >= qtile0 - 7); // h=1 valid
    floatx4 sf[2][4];
    __builtin_amdgcn_s_setprio(1);
#pragma unroll
    for (int nt = 0; nt < 4; ++nt) {
      bhalf8 k0 = *(const bhalf8*)&Ks[buf][(nt * 2) * 512 + (l15 * 4 + quad) * 8];
      bhalf8 k1 = *(const bhalf8*)&Ks[buf][(nt * 2 + 1) * 512 + (l15 * 4 + quad) * 8];
      floatx4 s0 = (floatx4){0.f, 0.f, 0.f, 0.f};
      floatx4 s1 = (floatx4){0.f, 0.f, 0.f, 0.f};
      if (va) {
        s0 = MFMA_BF16(k0, qa[0][0], s0);
        s0 = MFMA_BF16(k1, qa[0][1], s0);
      }
      if (vb_) {
        s1 = MFMA_BF16(k0, qa[1][0], s1);
        s1 = MFMA_BF16(k1, qa[1][1], s1);
      }
      sf[0][nt] = s0;
      sf[1][nt] = s1;
    }
    __builtin_amdgcn_s_setprio(0);

    half4 pf[2][4];
#pragma unroll
    for (int h = 0; h < 2; ++h) {
      if (!(h == 0 ? va : vb_)) continue;
      const int diag = qtile0 + h;
      const int iG = q0 + h * 64 + w * 16 + l15;
      if (kt == diag) {  // causal
#pragma unroll
        for (int nt = 0; nt < 4; ++nt) {
          int jb = kt * 64 + nt * 16 + quad * 4;
#pragma unroll
          for (int r = 0; r < 4; ++r)
            if (jb + r > iG) sf[h][nt][r] = -1e30f;
        }
      } else if (kt == diag - 8) {  // window edge
#pragma unroll
        for (int nt = 0; nt < 4; ++nt) {
          int jb = kt * 64 + nt * 16 + quad * 4;
#pragma unroll
          for (int r = 0; r < 4; ++r)
            if (jb + r + 512 < iG) sf[h][nt][r] = -1e30f;
        }
      }
#pragma unroll
      for (int nt = 0; nt < 4; ++nt) {
        float p0 = exp2f(sf[h][nt][0]);
        float p1 = exp2f(sf[h][nt][1]);
        float p2 = exp2f(sf[h][nt][2]);
        float p3 = exp2f(sf[h][nt][3]);
        lsum[h] += (p0 + p1) + (p2 + p3);
        union { half2 h2[2]; half4 h4; } pu;
        pu.h2[0] = cvt_pk_f16(p0, p1);
        pu.h2[1] = cvt_pk_f16(p2, p3);
        pf[h][nt] = pu.h4;
      }
    }

    __builtin_amdgcn_s_setprio(1);
#pragma unroll
    for (int nt = 0; nt < 4; ++nt) {
#pragma unroll
      for (int dt = 0; dt < 4; ++dt) {
        half4 vf = *(const half4*)&Vs[buf][(nt * 4 + dt) * 256 + (l15 * 4 + quad) * 4];
        if (va) O[0][dt] = MFMA_F16_K16(vf, pf[0][nt], O[0][dt]);
        if (vb_) O[1][dt] = MFMA_F16_K16(vf, pf[1][nt], O[1][dt]);
      }
    }
    __builtin_amdgcn_s_setprio(0);
  };

  int ktstart = qtile0 - 8;
  if (ktstart < 0) ktstart = 0;
  const int ktend = qtile0 + 1;
  const int ntot = ktend - ktstart + 1;  // even, 2..10 (block-uniform)

  // prologue: stage first two tiles, one-time FULL drain (also retires Q loads
  // so the compiler's waitcnt bookkeeping is clean for the loop).
  stage(ktstart, 0);
  stage(ktstart + 1, 1);
  __syncthreads();

  for (int i = 0; i < ntot; ++i) {
    const int kt = ktstart + i;
    if (i + 2 < ntot) {
      stage(kt + 2, (i + 2) & 3);
      asm volatile("s_waitcnt vmcnt(8)" ::: "memory");   // tile i landed; i+1,i+2 in flight
    } else if (i + 2 == ntot) {
      asm volatile("s_waitcnt vmcnt(4)" ::: "memory");   // only i+1 in flight
    } else {
      asm volatile("s_waitcnt vmcnt(0)" ::: "memory");   // last tile
    }
    __builtin_amdgcn_s_barrier();
    proc2(i & 3, kt);
  }

  const int b = bh >> 4, hh = bh & 15;
#pragma unroll
  for (int h = 0; h < 2; ++h) {
    float t = lsum[h];
    t += __shfl_xor(t, 16, 64);
    t += __shfl_xor(t, 32, 64);
    const float inv = 1.f / t;
    const int s = q0 + h * 64 + w * 16 + l15;
#pragma unroll
    for (int dt = 0; dt < 4; ++dt) {
      union { unsigned short u[4]; uint2 v2; } pk;
#pragma unroll
      for (int r = 0; r < 4; ++r) pk.u[r] = bfb(O[h][dt][r] * inv);
      *(uint2*)&attn_out[(size_t)(b * 2048 + s) * 1024 + hh * 64 + dt * 16 + quad * 4] = pk.v2;
    }
  }
}

// ---------------- host launch ----------------
extern "C" void kernel_launch(void* const* d_in, const int* in_sizes, int n_in,
                              void* d_out, int out_size, void* d_ws, size_t ws_size,
                              hipStream_t stream) {
  (void)in_sizes; (void)n_in; (void)out_size; (void)ws_size;
  const float* x = (const float*)d_in[0];
  const float* w_qkv = (const float*)d_in[1];
  const float* w_o = (const float*)d_in[2];
  float* out = (float*)d_out;
  char* ws = (char*)d_ws;

  bhalf* x_bf  = (bhalf*)(ws);                         // 8 MB
  bhalf* wqkvT = (bhalf*)(ws + ((size_t)8 << 20));     // 6 MB
  bhalf* woT   = (bhalf*)(ws + ((size_t)14 << 20));    // 2 MB
  bhalf* qb    = (bhalf*)(ws + ((size_t)16 << 20));    // 8 MB  [b,h,s,d] bf16 (pre-scaled)
  bhalf* kb    = (bhalf*)(ws + ((size_t)24 << 20));    // 8 MB  [b,h,s,d] bf16
  fh*    vb    = (fh*)(ws + ((size_t)32 << 20));       // 8 MB  [b,h,d,s] f16
  bhalf* attn  = (bhalf*)(ws + ((size_t)40 << 20));    // 8 MB

  prep_kernel<<<6144, 256, 0, stream>>>(x, w_qkv, w_o, x_bf, wqkvT, woT);
  gemm_bt_kernel<1, 128><<<dim3(24, 32), 256, 0, stream>>>(x_bf, wqkvT, nullptr, qb, kb, vb,
                                                           4096, 3072, 1024);
  attn_kernel<<<dim3(32, 16), 256, 0, stream>>>(qb, kb, vb, attn);
  gemm_bt_kernel<0, 64><<<dim3(16, 32), 256, 0, stream>>>(attn, woT, out, nullptr, nullptr,
                                                          nullptr, 4096, 1024, 1024);
}

// Round 7
// 158.144 us; speedup vs baseline: 1.0110x; 1.0110x over previous
//
#include <hip/hip_runtime.h>
#include <hip/hip_bf16.h>
#include <math.h>

typedef __bf16 bhalf;
typedef __bf16 bhalf8 __attribute__((ext_vector_type(8)));
typedef float floatx4 __attribute__((ext_vector_type(4)));
typedef _Float16 fh;
typedef _Float16 half2 __attribute__((ext_vector_type(2)));
typedef _Float16 half4 __attribute__((ext_vector_type(4)));

#define MFMA_BF16(A, B, C) __builtin_amdgcn_mfma_f32_16x16x32_bf16((A), (B), (C), 0, 0, 0)
#define MFMA_F16_K16(A, B, C) __builtin_amdgcn_mfma_f32_16x16x16f16((A), (B), (C), 0, 0, 0)

__device__ inline unsigned short bfb(float f) {
  union { bhalf h; unsigned short u; } c;
  c.h = (bhalf)f;
  return c.u;
}
__device__ inline unsigned short fhb(float f) {
  union { fh h; unsigned short u; } c;
  c.h = (fh)f;
  return c.u;
}
__device__ inline half2 cvt_pk_f16(float a, float b) {
  return __builtin_bit_cast(half2, __builtin_amdgcn_cvt_pkrtz(a, b));
}

// async global->LDS, 16B per lane; HW uses wave-uniform LDS base + lane*16
__device__ inline void gload_lds16(const void* g, void* l) {
  typedef const __attribute__((address_space(1))) unsigned int GU;
  typedef __attribute__((address_space(3))) unsigned int LU;
  __builtin_amdgcn_global_load_lds((GU*)g, (LU*)l, 16, 0, 0);
}

// ---------------- fused prep: cvt x (fp32->bf16) + both weight transposes -------
// blocks [0,2048): cvt_x ; [2048,5120): w_qkv^T ; [5120,6144): w_o^T
__global__ __launch_bounds__(256) void prep_kernel(const float* __restrict__ x,
                                                   const float* __restrict__ wqkv,
                                                   const float* __restrict__ wo,
                                                   bhalf* __restrict__ x_bf,
                                                   bhalf* __restrict__ wqkvT,
                                                   bhalf* __restrict__ woT) {
  __shared__ float tile[32][33];
  const int bx = blockIdx.x;
  if (bx < 2048) {
    int i = (bx * 256 + threadIdx.x) * 8;
    floatx4 v0 = *(const floatx4*)(x + i);
    floatx4 v1 = *(const floatx4*)(x + i + 4);
    bhalf8 o;
    o[0] = (bhalf)v0[0]; o[1] = (bhalf)v0[1]; o[2] = (bhalf)v0[2]; o[3] = (bhalf)v0[3];
    o[4] = (bhalf)v1[0]; o[5] = (bhalf)v1[1]; o[6] = (bhalf)v1[2]; o[7] = (bhalf)v1[3];
    *(bhalf8*)(x_bf + i) = o;
    return;
  }
  const float* in;
  bhalf* out;
  int C, cx, ry;
  if (bx < 5120) {
    int idx = bx - 2048;
    in = wqkv; out = wqkvT; C = 3072;
    cx = idx % 96; ry = idx / 96;
  } else {
    int idx = bx - 5120;
    in = wo; out = woT; C = 1024;
    cx = idx & 31; ry = idx >> 5;
  }
  const int R = 1024;
  int c0 = cx * 32, r0 = ry * 32;
  int tx = threadIdx.x & 31, ty = threadIdx.x >> 5;
#pragma unroll
  for (int i = 0; i < 32; i += 8)
    tile[ty + i][tx] = in[(size_t)(r0 + ty + i) * C + c0 + tx];
  __syncthreads();
#pragma unroll
  for (int i = 0; i < 32; i += 8)
    out[(size_t)(c0 + ty + i) * R + r0 + tx] = (bhalf)tile[tx][ty + i];
}

// ---------------- GEMM: C[M,N] = A[M,K] * BT[N,K]^T  (bf16 in, fp32 acc) --------
// r5 structure: BK=64, SINGLE 32KB LDS buffer, 2 barriers/iter, co-resident
// blocks do the latency hiding.
// r10: RoPE via __sincosf base + 3-step angle-addition recurrence.
// r12 (T1): XCD-chunked 1-D grid. R3 counters showed MfmaUtil/VALU/HBM ALL low
//   -> memory-system bound: consecutive blocks sharing A/B panels round-robin
//   across 8 XCDs, so every panel is re-fetched into every XCD's L2 from L3
//   (~112MB L3->L2; HBM FETCH hides it at 38MB). Remap: XCD k owns m-tiles
//   4k..4k+3 (A-chunk 1MB L2-resident), m-fastest order so each B panel is
//   reused 4x back-to-back from L2. Bijective: 8 * (nmt/8) * nnt = nmt*nnt.
template <int EPI, int TN>
__global__ __launch_bounds__(256, 2) void gemm_bt_kernel(
    const bhalf* __restrict__ A, const bhalf* __restrict__ BT, float* __restrict__ Cout,
    bhalf* __restrict__ qb, bhalf* __restrict__ kb, fh* __restrict__ vb,
    int M, int N, int K) {
  constexpr int NT = TN / 32;
  __shared__ __attribute__((aligned(16))) bhalf As[128 * 64];  // 16 KB
  __shared__ __attribute__((aligned(16))) bhalf Bs[TN * 64];   // 16/8 KB
  const int tid = threadIdx.x;
  const int lane = tid & 63;
  const int w = tid >> 6, wr = w >> 1, wc = w & 1;

  // T1 XCD-chunked swizzle (1-D grid = nmt*nnt blocks)
  const int nmt = M >> 7;           // m-tiles (32)
  const int mchunk = nmt >> 3;      // m-tiles per XCD chunk (4)
  const int lin = blockIdx.x;
  const int xcd = lin & 7, idx = lin >> 3;
  const int m_t = xcd * mchunk + (idx & (mchunk - 1));
  const int n_t = idx / mchunk;
  const int m0 = m_t * 128, n0 = n_t * TN;

  const int l15 = lane & 15, lhi = lane >> 4;

  floatx4 acc[4][NT];
#pragma unroll
  for (int i = 0; i < 4; ++i)
#pragma unroll
    for (int j = 0; j < NT; ++j) acc[i][j] = (floatx4){0.f, 0.f, 0.f, 0.f};

  const int srow16 = lane >> 2;
  const int scg = (lane & 3) ^ ((lane >> 3) & 3);
  const bhalf* aP0 = A + (size_t)(m0 + 32 * w + srow16) * K + scg * 8;
  const bhalf* aP1 = aP0 + (size_t)16 * K;
  const bhalf* bP0 = BT + (size_t)(n0 + ((TN == 128) ? 32 * w : 16 * w) + srow16) * K + scg * 8;
  const bhalf* bP1 = bP0 + (size_t)16 * K;
  bhalf* aL0 = &As[(2 * w) * 512];
  bhalf* aL1 = &As[(2 * w + 1) * 512];
  bhalf* bL0 = (TN == 128) ? &Bs[(2 * w) * 512] : &Bs[w * 512];
  bhalf* bL1 = (TN == 128) ? &Bs[(2 * w + 1) * 512] : nullptr;

  const int fro = (l15 * 4 + (lhi ^ ((l15 >> 1) & 3))) * 8;

  for (int k0 = 0; k0 < K; k0 += 64) {
    __syncthreads();
    // k-half 0 (cols k0..k0+31)
    gload_lds16(aP0 + k0, aL0);
    gload_lds16(aP1 + k0, aL1);
    gload_lds16(bP0 + k0, bL0);
    if constexpr (TN == 128) gload_lds16(bP1 + k0, bL1);
    // k-half 1 (cols k0+32..k0+63) -> LDS +4096 (A) / +TN*32 (B)
    gload_lds16(aP0 + k0 + 32, aL0 + 4096);
    gload_lds16(aP1 + k0 + 32, aL1 + 4096);
    gload_lds16(bP0 + k0 + 32, bL0 + TN * 32);
    if constexpr (TN == 128) gload_lds16(bP1 + k0 + 32, bL1 + TN * 32);
    __syncthreads();
#pragma unroll
    for (int kh = 0; kh < 2; ++kh) {
      bhalf8 af[4], bf[NT];
#pragma unroll
      for (int mt = 0; mt < 4; ++mt)
        af[mt] = *(const bhalf8*)&As[kh * 4096 + (wr * 4 + mt) * 512 + fro];
#pragma unroll
      for (int nt = 0; nt < NT; ++nt)
        bf[nt] = *(const bhalf8*)&Bs[kh * TN * 32 + (wc * NT + nt) * 512 + fro];
#pragma unroll
      for (int mt = 0; mt < 4; ++mt)
#pragma unroll
        for (int nt = 0; nt < NT; ++nt)
          acc[mt][nt] = MFMA_BF16(af[mt], bf[nt], acc[mt][nt]);
    }
  }

  if constexpr (EPI == 0) {
#pragma unroll
    for (int mt = 0; mt < 4; ++mt)
#pragma unroll
      for (int nt = 0; nt < NT; ++nt)
#pragma unroll
        for (int r = 0; r < 4; ++r) {
          int mg = m0 + wr * 64 + mt * 16 + lhi * 4 + r;
          int ng = n0 + wc * (TN / 2) + nt * 16 + l15;
          Cout[(size_t)mg * N + ng] = acc[mt][nt][r];
        }
  } else {
    const int sel = n0 >> 10;  // block-uniform: 0=q, 1=k, 2=v
    if (sel == 2) {
      // v: store transposed [b,h,d,s] as f16 -- 4 s-contiguous per lane = 8B store
#pragma unroll
      for (int mt = 0; mt < 4; ++mt) {
        int mg = m0 + wr * 64 + mt * 16 + lhi * 4;
        int b = mg >> 11, s0 = mg & 2047;
#pragma unroll
        for (int nt = 0; nt < NT; ++nt) {
          int ng = n0 + wc * (TN / 2) + nt * 16 + l15;
          int h = (ng & 1023) >> 6, d = ng & 63;
          union { unsigned short u[4]; uint2 v2; } pk;
#pragma unroll
          for (int r = 0; r < 4; ++r) pk.u[r] = fhb(acc[mt][nt][r]);
          *(uint2*)&vb[((size_t)((b << 4) + h) * 64 + d) * 2048 + s0] = pk.v2;
        }
      }
    } else {
      bhalf* dst = sel ? kb : qb;
      const float post = sel ? 1.0f : 0.18033688f;  // q pre-scaled by 0.125*log2(e)
#pragma unroll
      for (int nt = 0; nt < NT; ++nt) {
        int ng = n0 + wc * (TN / 2) + nt * 16 + l15;
        int h = (ng & 1023) >> 6, d = ng & 63;
        float inv = exp2f((float)(d >> 1) * -0.4152410118609203f);
        float si, ci;
        __sincosf(inv, &si, &ci);  // per-row rotation step
#pragma unroll
        for (int mt = 0; mt < 4; ++mt) {
          int mg = m0 + wr * 64 + mt * 16 + lhi * 4;
          int b = mg >> 11, s0 = mg & 2047;
          float sn, cs;
          __sincosf((float)s0 * inv, &sn, &cs);
#pragma unroll
          for (int r = 0; r < 4; ++r) {
            float val = acc[mt][nt][r];
            float partner = __shfl_xor(val, 1, 64);  // pair column d^1 lives in lane^1
            if (!(l15 & 1)) {
              float oe = (cs * val - sn * partner) * post;
              float oo = (cs * partner + sn * val) * post;
              unsigned int u = bfb(oe) | ((unsigned int)bfb(oo) << 16);
              *(unsigned int*)&dst[((size_t)((b << 4) + h) * 2048 + (s0 + r)) * 64 + d] = u;
            }
            // angle-addition recurrence: (cs,sn) <- rot by inv
            float cs2 = cs * ci - sn * si;
            sn = sn * ci + cs * si;
            cs = cs2;
          }
        }
      }
    }
  }
}

// ---------------- flash sliding-window attention ----------------
// 1-D grid 512, 256 thr = 4 waves. Q-tile 128 rows (two 64-halves share the
// staged K/V and the LDS fragment reads). S^T trick (A=K,B=Q): C-layout == f16
// B-operand layout -> P stays in registers. No-max softmax; q pre-scaled.
// r11: 4 LDS buffers (64KB), prefetch depth 2, counted vmcnt, one barrier/tile.
// r12 (T1): XCD-chunked swizzle -- XCD k owns heads 4k..4k+3, so its K/V
//   working set (4 x 512KB = 2MB) is L2-resident; previously the 16 q-tile
//   blocks of a head were spread across all 8 XCDs (every stage = L3 fetch).
__global__ __launch_bounds__(256, 2) void attn_kernel(const bhalf* __restrict__ qg,
                                                      const bhalf* __restrict__ kg,
                                                      const fh* __restrict__ vt,
                                                      bhalf* __restrict__ attn_out) {
  __shared__ __attribute__((aligned(16))) bhalf Ks[4][8 * 512];  // 4 x 8 KB
  __shared__ __attribute__((aligned(16))) fh Vs[4][16 * 256];    // 4 x 8 KB

  // T1 swizzle: lin -> (bh, qt2); XCD k gets heads 4k..4k+3 (bijective, 512=8*4*16)
  const int lin = blockIdx.x;
  const int xcd = lin & 7, idx = lin >> 3;
  const int bh = xcd * 4 + (idx & 3);   // b*16+h
  const int qt2 = idx >> 2;             // 128-row q tile

  const int tid = threadIdx.x, lane = tid & 63, w = tid >> 6;
  const int l15 = lane & 15, quad = lane >> 4;
  const int q0 = qt2 * 128;
  const int qtile0 = qt2 * 2;   // 64-granular tile index of first half (even)
  const size_t base = (size_t)bh * 2048 * 64;   // q,k: [bh][s][d]
  const size_t vbase = (size_t)bh * 64 * 2048;  // vt:  [bh][d][s]

  // Q B-fragments for both halves (already scaled by 0.125*log2e in qkv epilogue)
  bhalf8 qa[2][2];
#pragma unroll
  for (int h = 0; h < 2; ++h) {
    const bhalf* qp = qg + base + (size_t)(q0 + h * 64 + w * 16 + l15) * 64 + quad * 8;
    qa[h][0] = *(const bhalf8*)qp;
    qa[h][1] = *(const bhalf8*)(qp + 32);
  }

  // DMA lane-geometry (tile-offset-independent)
  const int kOff = (w * 16 + (lane >> 2)) * 64 + (lane & 3) * 8;
  const int vfb0 = 4 * w + (lane >> 5), vfb1 = 4 * w + 2 + (lane >> 5);
  const int vOff0 = ((vfb0 & 3) * 16 + ((lane & 31) >> 1)) * 2048 + w * 16 + (lane & 1) * 8;
  const int vOff1 = ((vfb1 & 3) * 16 + ((lane & 31) >> 1)) * 2048 + w * 16 + (lane & 1) * 8;

  floatx4 O[2][4];
#pragma unroll
  for (int h = 0; h < 2; ++h)
#pragma unroll
    for (int dt = 0; dt < 4; ++dt) O[h][dt] = (floatx4){0.f, 0.f, 0.f, 0.f};
  float lsum[2] = {0.f, 0.f};

  auto stage = [&](int kt, int buf) {  // 4 gload_lds16 per wave
    const bhalf* kp = kg + base + (size_t)(kt * 64) * 64 + kOff;
    gload_lds16(kp, &Ks[buf][(2 * w) * 512]);
    gload_lds16(kp + 32, &Ks[buf][(2 * w + 1) * 512]);
    const fh* vp = vt + vbase + kt * 64;
    gload_lds16(vp + vOff0, &Vs[buf][(2 * w) * 512]);
    gload_lds16(vp + vOff1, &Vs[buf][(2 * w + 1) * 512]);
  };

  // one 64-key tile, BOTH q-halves, sharing every K/V fragment read
  auto proc2 = [&](int buf, int kt) {
    const bool va = (kt <= qtile0) && (kt >= qtile0 - 8);      // h=0 valid
    const bool vb_ = (kt <= qtile0 + 1) && (kt >= qtile0 - 7); // h=1 valid
    floatx4 sf[2][4];
    __builtin_amdgcn_s_setprio(1);
#pragma unroll
    for (int nt = 0; nt < 4; ++nt) {
      bhalf8 k0 = *(const bhalf8*)&Ks[buf][(nt * 2) * 512 + (l15 * 4 + quad) * 8];
      bhalf8 k1 = *(const bhalf8*)&Ks[buf][(nt * 2 + 1) * 512 + (l15 * 4 + quad) * 8];
      floatx4 s0 = (floatx4){0.f, 0.f, 0.f, 0.f};
      floatx4 s1 = (floatx4){0.f, 0.f, 0.f, 0.f};
      if (va) {
        s0 = MFMA_BF16(k0, qa[0][0], s0);
        s0 = MFMA_BF16(k1, qa[0][1], s0);
      }
      if (vb_) {
        s1 = MFMA_BF16(k0, qa[1][0], s1);
        s1 = MFMA_BF16(k1, qa[1][1], s1);
      }
      sf[0][nt] = s0;
      sf[1][nt] = s1;
    }
    __builtin_amdgcn_s_setprio(0);

    half4 pf[2][4];
#pragma unroll
    for (int h = 0; h < 2; ++h) {
      if (!(h == 0 ? va : vb_)) continue;
      const int diag = qtile0 + h;
      const int iG = q0 + h * 64 + w * 16 + l15;
      if (kt == diag) {  // causal
#pragma unroll
        for (int nt = 0; nt < 4; ++nt) {
          int jb = kt * 64 + nt * 16 + quad * 4;
#pragma unroll
          for (int r = 0; r < 4; ++r)
            if (jb + r > iG) sf[h][nt][r] = -1e30f;
        }
      } else if (kt == diag - 8) {  // window edge
#pragma unroll
        for (int nt = 0; nt < 4; ++nt) {
          int jb = kt * 64 + nt * 16 + quad * 4;
#pragma unroll
          for (int r = 0; r < 4; ++r)
            if (jb + r + 512 < iG) sf[h][nt][r] = -1e30f;
        }
      }
#pragma unroll
      for (int nt = 0; nt < 4; ++nt) {
        float p0 = exp2f(sf[h][nt][0]);
        float p1 = exp2f(sf[h][nt][1]);
        float p2 = exp2f(sf[h][nt][2]);
        float p3 = exp2f(sf[h][nt][3]);
        lsum[h] += (p0 + p1) + (p2 + p3);
        union { half2 h2[2]; half4 h4; } pu;
        pu.h2[0] = cvt_pk_f16(p0, p1);
        pu.h2[1] = cvt_pk_f16(p2, p3);
        pf[h][nt] = pu.h4;
      }
    }

    __builtin_amdgcn_s_setprio(1);
#pragma unroll
    for (int nt = 0; nt < 4; ++nt) {
#pragma unroll
      for (int dt = 0; dt < 4; ++dt) {
        half4 vf = *(const half4*)&Vs[buf][(nt * 4 + dt) * 256 + (l15 * 4 + quad) * 4];
        if (va) O[0][dt] = MFMA_F16_K16(vf, pf[0][nt], O[0][dt]);
        if (vb_) O[1][dt] = MFMA_F16_K16(vf, pf[1][nt], O[1][dt]);
      }
    }
    __builtin_amdgcn_s_setprio(0);
  };

  int ktstart = qtile0 - 8;
  if (ktstart < 0) ktstart = 0;
  const int ktend = qtile0 + 1;
  const int ntot = ktend - ktstart + 1;  // even, 2..10 (block-uniform)

  // prologue: stage first two tiles, one-time FULL drain (also retires Q loads
  // so the compiler's waitcnt bookkeeping is clean for the loop).
  stage(ktstart, 0);
  stage(ktstart + 1, 1);
  __syncthreads();

  for (int i = 0; i < ntot; ++i) {
    const int kt = ktstart + i;
    if (i + 2 < ntot) {
      stage(kt + 2, (i + 2) & 3);
      asm volatile("s_waitcnt vmcnt(8)" ::: "memory");   // tile i landed; i+1,i+2 in flight
    } else if (i + 2 == ntot) {
      asm volatile("s_waitcnt vmcnt(4)" ::: "memory");   // only i+1 in flight
    } else {
      asm volatile("s_waitcnt vmcnt(0)" ::: "memory");   // last tile
    }
    __builtin_amdgcn_s_barrier();
    proc2(i & 3, kt);
  }

  const int b = bh >> 4, hh = bh & 15;
#pragma unroll
  for (int h = 0; h < 2; ++h) {
    float t = lsum[h];
    t += __shfl_xor(t, 16, 64);
    t += __shfl_xor(t, 32, 64);
    const float inv = 1.f / t;
    const int s = q0 + h * 64 + w * 16 + l15;
#pragma unroll
    for (int dt = 0; dt < 4; ++dt) {
      union { unsigned short u[4]; uint2 v2; } pk;
#pragma unroll
      for (int r = 0; r < 4; ++r) pk.u[r] = bfb(O[h][dt][r] * inv);
      *(uint2*)&attn_out[(size_t)(b * 2048 + s) * 1024 + hh * 64 + dt * 16 + quad * 4] = pk.v2;
    }
  }
}

// ---------------- host launch ----------------
extern "C" void kernel_launch(void* const* d_in, const int* in_sizes, int n_in,
                              void* d_out, int out_size, void* d_ws, size_t ws_size,
                              hipStream_t stream) {
  (void)in_sizes; (void)n_in; (void)out_size; (void)ws_size;
  const float* x = (const float*)d_in[0];
  const float* w_qkv = (const float*)d_in[1];
  const float* w_o = (const float*)d_in[2];
  float* out = (float*)d_out;
  char* ws = (char*)d_ws;

  bhalf* x_bf  = (bhalf*)(ws);                         // 8 MB
  bhalf* wqkvT = (bhalf*)(ws + ((size_t)8 << 20));     // 6 MB
  bhalf* woT   = (bhalf*)(ws + ((size_t)14 << 20));    // 2 MB
  bhalf* qb    = (bhalf*)(ws + ((size_t)16 << 20));    // 8 MB  [b,h,s,d] bf16 (pre-scaled)
  bhalf* kb    = (bhalf*)(ws + ((size_t)24 << 20));    // 8 MB  [b,h,s,d] bf16
  fh*    vb    = (fh*)(ws + ((size_t)32 << 20));       // 8 MB  [b,h,d,s] f16
  bhalf* attn  = (bhalf*)(ws + ((size_t)40 << 20));    // 8 MB

  prep_kernel<<<6144, 256, 0, stream>>>(x, w_qkv, w_o, x_bf, wqkvT, woT);
  gemm_bt_kernel<1, 128><<<768, 256, 0, stream>>>(x_bf, wqkvT, nullptr, qb, kb, vb,
                                                  4096, 3072, 1024);
  attn_kernel<<<512, 256, 0, stream>>>(qb, kb, vb, attn);
  gemm_bt_kernel<0, 64><<<512, 256, 0, stream>>>(attn, woT, out, nullptr, nullptr,
                                                 nullptr, 4096, 1024, 1024);
}